// Round 11
// baseline (256.495 us; speedup 1.0000x reference)
//
#include <hip/hip_runtime.h>
#include <hip/hip_fp16.h>

typedef _Float16 f16x8 __attribute__((ext_vector_type(8)));
typedef float f32x4 __attribute__((ext_vector_type(4)));

__device__ __forceinline__ unsigned short f2h_bits(float f) {
    __half h = __float2half(f);
    return *reinterpret_cast<unsigned short*>(&h);
}
__device__ __forceinline__ float h2f_bits(unsigned short u) {
    __half h = *reinterpret_cast<__half*>(&u);
    return __half2float(h);
}

// acc += a(f32) * f16_lo(hw)  -- one VOP3P v_fma_mix_f32
__device__ __forceinline__ void fma_mix_lo(float& acc, float a, unsigned hw) {
    asm("v_fma_mix_f32 %0, %1, %2, %0 op_sel_hi:[0,1,0]"
        : "+v"(acc) : "v"(a), "v"(hw));
}
// acc += a(f32) * f16_hi(hw)
__device__ __forceinline__ void fma_mix_hi(float& acc, float a, unsigned hw) {
    asm("v_fma_mix_f32 %0, %1, %2, %0 op_sel:[0,1,0] op_sel_hi:[0,1,0]"
        : "+v"(acc) : "v"(a), "v"(hw));
}

// fast ELU: x>0 ? x : e^x-1  (exp never NaN; select discards the inf branch)
__device__ __forceinline__ float elu_fast(float v) {
    float e = __expf(v) - 1.f;
    return v > 0.f ? v : e;
}

// async 16B global->LDS (DMA path, no VGPR round-trip). LDS dest is
// wave-uniform base + lane*16 (HW rule) -- layout below is linear in lane order.
__device__ __forceinline__ void gload_lds16(const void* g, void* l) {
    __builtin_amdgcn_global_load_lds(
        (const __attribute__((address_space(1))) unsigned int*)g,
        (__attribute__((address_space(3))) unsigned int*)l, 16, 0, 0);
}

// ---------------- prep: W transposes (fp16) + was/wad fold, x cvt, csr, deg --
// was[k,h] = sum_c W[k,128h+c]*a_src[h,c] (f32 math, fp16 store): attention
// logits become 8 extra GEMM columns (R8 structure). R11: x cvt via float4
// (4 elems/thread) and csr init via int4 -- prep thread count 3.7M -> 1.5M.
// csr-init int4 tail may overrun into cur[] pad: harmless, k_alloc fully
// rewrites cur before any use. deg (+tot) zeroed by hipMemsetAsync.
__global__ void k_prep(const float* __restrict__ W1, unsigned short* __restrict__ W1T,
                       const float* __restrict__ W2, unsigned short* __restrict__ W2T,
                       const float* __restrict__ W3, unsigned short* __restrict__ W3T,
                       const float* __restrict__ x, unsigned short* __restrict__ xb,
                       int* __restrict__ csr, int Mcap,
                       const int* __restrict__ ei, int E, int* __restrict__ deg,
                       const float* __restrict__ as1, const float* __restrict__ ad1,
                       const float* __restrict__ as2, const float* __restrict__ ad2,
                       int DIN, int HC, int DOUT, int N)
{
    int i = blockIdx.x * blockDim.x + threadIdx.x;
    int n1 = DIN * HC;
    int n2 = n1 + HC * HC;
    int n3 = n2 + HC * DOUT;
    int n4 = n3 + ((N * DIN) >> 2);      // x cvt, float4 granularity
    int n5 = n4 + ((Mcap + 3) >> 2);     // csr init, int4 granularity
    int n6 = n5 + E;
    int n7 = n6 + 8 * DIN;               // was1/wad1
    int n8 = n7 + 8 * HC;                // was2/wad2
    int n9 = n8 + 56 * DIN + 56 * HC;    // zero pad rows 520..575
    if (i < n1) {
        int k = i / HC, n = i - k * HC;
        W1T[n * DIN + k] = f2h_bits(W1[i]);
    } else if (i < n2) {
        int j = i - n1;
        int k = j / HC, n = j - k * HC;
        W2T[n * HC + k] = f2h_bits(W2[j]);
    } else if (i < n3) {
        int j = i - n2;
        int k = j / DOUT, n = j - k * DOUT;
        W3T[n * HC + k] = f2h_bits(W3[j]);
    } else if (i < n4) {
        int j = i - n3;
        float4 v = *(const float4*)(x + 4 * (size_t)j);
        unsigned lo = (unsigned)f2h_bits(v.x) | ((unsigned)f2h_bits(v.y) << 16);
        unsigned hi = (unsigned)f2h_bits(v.z) | ((unsigned)f2h_bits(v.w) << 16);
        uint2 o; o.x = lo; o.y = hi;
        *(uint2*)(xb + 4 * (size_t)j) = o;
    } else if (i < n5) {
        int j = i - n4;
        int4 mm; mm.x = -1; mm.y = -1; mm.z = -1; mm.w = -1;
        *(int4*)(csr + 4 * (size_t)j) = mm;   // pad sentinel
    } else if (i < n6) {
        atomicAdd(&deg[ei[E + (i - n5)]], 1);
    } else if (i < n7) {
        int j = i - n6;
        int h8 = j / DIN, k = j - h8 * DIN;
        int hh = h8 & 3;
        const float* av = (h8 < 4 ? as1 : ad1) + hh * 128;
        const float* wr = W1 + (size_t)k * HC + hh * 128;
        float s = 0.f;
        for (int c = 0; c < 128; ++c) s += wr[c] * av[c];
        W1T[(size_t)(HC + h8) * DIN + k] = f2h_bits(s);
    } else if (i < n8) {
        int j = i - n7;
        int h8 = j / HC, k = j - h8 * HC;
        int hh = h8 & 3;
        const float* av = (h8 < 4 ? as2 : ad2) + hh * 128;
        const float* wr = W2 + (size_t)k * HC + hh * 128;
        float s = 0.f;
        for (int c = 0; c < 128; ++c) s += wr[c] * av[c];
        W2T[(size_t)(HC + h8) * HC + k] = f2h_bits(s);
    } else if (i < n9) {
        int j = i - n8;
        if (j < 56 * DIN) W1T[(size_t)(HC + 8) * DIN + j] = 0;
        else              W2T[(size_t)(HC + 8) * HC + (j - 56 * DIN)] = 0;
    }
}

// ---------------- parallel segment allocator ------------------------------
// Segment ORDER is irrelevant (aggr derives length from deg[n]); per-wave
// inclusive shfl-scan + ONE atomicAdd per wave assigns bases (R10: replaced
// the serial single-workgroup scan, -9us).
__global__ void k_alloc(const int* __restrict__ deg, int* __restrict__ off,
                        int* __restrict__ cur, int* __restrict__ tot, int N)
{
    int i = blockIdx.x * blockDim.x + threadIdx.x;
    int lane = threadIdx.x & 63;
    int sz = (i < N) ? ((deg[i] + 4) & ~3) : 0;
    int run = sz;
#pragma unroll
    for (int d = 1; d < 64; d <<= 1) {
        int v = __shfl_up(run, d);
        if (lane >= d) run += v;
    }
    int wtot = __shfl(run, 63);
    int base = 0;
    if (lane == 63) base = atomicAdd(tot, wtot);
    base = __shfl(base, 63);
    if (i < N) {
        int p = base + run - sz;   // exclusive within wave
        off[i] = p;
        cur[i] = p;
    }
}

__global__ void k_fill(const int* __restrict__ ei, int E, int N,
                       int* cur, int* __restrict__ csr) {
    int i = blockIdx.x * blockDim.x + threadIdx.x;
    if (i < E) {
        int s = ei[i], d = ei[E + i];
        int pos = atomicAdd(&cur[d], 1);
        csr[pos] = s;
    } else if (i < E + N) {
        int nn = i - E;
        int pos = atomicAdd(&cur[nn], 1);
        csr[pos] = nn;
    }
}

// ---------------- GEMM (layer 3 / small-Nc path): register-only 64x64, fp16 --
// DOAL: fused attention-logit epilogue (valid only when tiles_n==1, i.e. the
// wave's 64 cols are ALL output cols; layer 3, H=1). Per row:
// al_s[row] = sum_col acc*a_src -> 4 FMA + shfl_xor reduce over the 16 r-lanes.
template <bool OUTH, bool DOAL>
__global__ __launch_bounds__(256) void k_gemm(
    const unsigned short* __restrict__ A, const unsigned short* __restrict__ BT,
    void* __restrict__ D, int M, int K, int Nc, int tiles_n,
    const float* __restrict__ asrc, const float* __restrict__ adst,
    float* __restrict__ als, float* __restrict__ ald)
{
    int wid = blockIdx.x * (blockDim.x >> 6) + (threadIdx.x >> 6);
    int tiles_m = (M + 63) >> 6;
    if (wid >= tiles_m * tiles_n) return;
    int lane = threadIdx.x & 63;
    int tm = wid / tiles_n, tn = wid - tm * tiles_n;
    int m0 = tm << 6, n0 = tn << 6;
    int r = lane & 15, q = lane >> 4;

    const unsigned short* Arow[4];
    const unsigned short* Brow[4];
#pragma unroll
    for (int i = 0; i < 4; ++i) {
        int row = m0 + 16 * i + r; row = row < M ? row : M - 1;
        Arow[i] = A + (size_t)row * K + q * 8;
        Brow[i] = BT + (size_t)(n0 + 16 * i + r) * K + q * 8;
    }

    f32x4 acc[4][4] = {};
    f16x8 a[4], b[4], a2[4], b2[4];
#pragma unroll
    for (int i = 0; i < 4; ++i) {
        a[i] = *(const f16x8*)(Arow[i]);
        b[i] = *(const f16x8*)(Brow[i]);
    }
    for (int k0 = 0; k0 < K; k0 += 32) {
        int kn = k0 + 32;
        if (kn < K) {
#pragma unroll
            for (int i = 0; i < 4; ++i) {
                a2[i] = *(const f16x8*)(Arow[i] + kn);
                b2[i] = *(const f16x8*)(Brow[i] + kn);
            }
        }
#pragma unroll
        for (int i = 0; i < 4; ++i)
#pragma unroll
            for (int j = 0; j < 4; ++j)
                acc[i][j] = __builtin_amdgcn_mfma_f32_16x16x32_f16(a[i], b[j], acc[i][j], 0, 0, 0);
        if (kn < K) {
#pragma unroll
            for (int i = 0; i < 4; ++i) { a[i] = a2[i]; b[i] = b2[i]; }
        }
    }
#pragma unroll
    for (int i = 0; i < 4; ++i) {
        int rowb = m0 + 16 * i + q * 4;
#pragma unroll
        for (int rr = 0; rr < 4; ++rr) {
            int row = rowb + rr;
            if (row < M) {
#pragma unroll
                for (int j = 0; j < 4; ++j) {
                    int col = n0 + 16 * j + r;
                    if (OUTH)
                        ((unsigned short*)D)[(size_t)row * Nc + col] = f2h_bits(acc[i][j][rr]);
                    else
                        ((float*)D)[(size_t)row * Nc + col] = acc[i][j][rr];
                }
            }
        }
    }
    if (DOAL) {
        float asl[4], adl[4];
#pragma unroll
        for (int j = 0; j < 4; ++j) { asl[j] = asrc[16 * j + r]; adl[j] = adst[16 * j + r]; }
#pragma unroll
        for (int i = 0; i < 4; ++i) {
#pragma unroll
            for (int rr = 0; rr < 4; ++rr) {
                float s = 0.f, d = 0.f;
#pragma unroll
                for (int j = 0; j < 4; ++j) {
                    s += acc[i][j][rr] * asl[j];
                    d += acc[i][j][rr] * adl[j];
                }
#pragma unroll
                for (int dd = 1; dd < 16; dd <<= 1) {
                    s += __shfl_xor(s, dd);
                    d += __shfl_xor(d, dd);
                }
                int row = m0 + 16 * i + q * 4 + rr;
                if (r == 0 && row < M) { als[row] = s; ald[row] = d; }
            }
        }
    }
}

// ---------------- GEMM (layers 1&2): m97-style 128x64 tile, LDS-staged, fp16 --
// 4 waves (2x2), wave tile 64x32, BK=32. Staging via global_load_lds width 16.
// tiles_n = HC/64 + 1: the LAST column-tile multiplies the was/wad extension
// rows of BT (512..519; 520..575 zero), so its accumulators ARE the attention
// logits -- epilogue writes als/ald (f32, exclusive). R8-proven structure;
// R9's dbuf+atomics variant regressed (+30us) -- do not re-add.
__global__ __launch_bounds__(256) void k_gemm_lds(
    const unsigned short* __restrict__ A, const unsigned short* __restrict__ BT,
    unsigned short* __restrict__ D, int M, int K, int Nc, int tiles_n,
    float* __restrict__ als, float* __restrict__ ald)
{
    __shared__ unsigned short As[128 * 32];   // 8 KiB
    __shared__ unsigned short Bs[64 * 32];    // 4 KiB
    int tm = blockIdx.x / tiles_n, tn = blockIdx.x - tm * tiles_n;
    int m0 = tm << 7, n0 = tn << 6;
    int tid = threadIdx.x;
    int w = tid >> 6, lane = tid & 63;
    int wr = w >> 1, wc = w & 1;
    int r = lane & 15, q = lane >> 4;

    // staging: chunk c = 16 tile-rows; lane l -> row c*16 + l/4, bytes (l&3)*16
    int lrow = lane >> 2;
    int lch = (lane & 3) * 8;                  // in fp16 elements
    int ga0 = m0 + w * 16 + lrow;       if (ga0 >= M) ga0 = M - 1;
    int ga1 = m0 + (w + 4) * 16 + lrow; if (ga1 >= M) ga1 = M - 1;
    const unsigned short* pa0 = A + (size_t)ga0 * K + lch;
    const unsigned short* pa1 = A + (size_t)ga1 * K + lch;
    const unsigned short* pb  = BT + (size_t)(n0 + w * 16 + lrow) * K + lch;
    unsigned short* lA0 = As + w * 512;        // wave-uniform LDS chunk bases
    unsigned short* lA1 = As + (w + 4) * 512;
    unsigned short* lB  = Bs + w * 512;

    const unsigned short* arp = As + (wr * 64 + r) * 32 + q * 8;
    const unsigned short* brp = Bs + (wc * 32 + r) * 32 + q * 8;

    f32x4 acc[4][2] = {};
    for (int k0 = 0; k0 < K; k0 += 32) {
        gload_lds16(pa0 + k0, lA0);
        gload_lds16(pa1 + k0, lA1);
        gload_lds16(pb + k0, lB);
        __syncthreads();                        // compiler drains vmcnt(0) here
        f16x8 a[4], b[2];
#pragma unroll
        for (int i = 0; i < 4; ++i) a[i] = *(const f16x8*)(arp + i * 16 * 32);
#pragma unroll
        for (int j = 0; j < 2; ++j) b[j] = *(const f16x8*)(brp + j * 16 * 32);
#pragma unroll
        for (int i = 0; i < 4; ++i)
#pragma unroll
            for (int j = 0; j < 2; ++j)
                acc[i][j] = __builtin_amdgcn_mfma_f32_16x16x32_f16(a[i], b[j], acc[i][j], 0, 0, 0);
        __syncthreads();                        // protect LDS before next stage
    }
    if (tn == tiles_n - 1) {
        // al tile: col r (wc==0, j==0) maps to BT row 512+r: r<4 -> als head r,
        // r in 4..7 -> ald head r-4. Exclusive f32 writes, no atomics.
        if (wc == 0 && r < 8) {
            float* dst = (r < 4) ? als : ald;
            int hh = r & 3;
#pragma unroll
            for (int i = 0; i < 4; ++i)
#pragma unroll
                for (int rr = 0; rr < 4; ++rr) {
                    int row = m0 + wr * 64 + 16 * i + q * 4 + rr;
                    if (row < M) dst[row * 4 + hh] = acc[i][0][rr];
                }
        }
        return;
    }
#pragma unroll
    for (int i = 0; i < 4; ++i) {
        int rowb = m0 + wr * 64 + 16 * i + q * 4;
#pragma unroll
        for (int rr = 0; rr < 4; ++rr) {
            int row = rowb + rr;
            if (row < M) {
#pragma unroll
                for (int j = 0; j < 2; ++j) {
                    int col = n0 + wc * 32 + 16 * j + r;
                    D[(size_t)row * Nc + col] = f2h_bits(acc[i][j][rr]);
                }
            }
        }
    }
}

// ---------------- aggr HC=512 H=4: PERSISTENT waves, slab, prepass ---------
// R11: grid = 2048 blocks (exactly 8/CU co-resident); each wave statically
// strides items it = wgid + k*8192 over the 4N (node,head) items in
// HEAD-MAJOR order (preserves the 2.56MB/XCD L2 plane working set -- the
// gather target set depends on the head offset, not the node window).
// Rationale: R6 counters showed Occupancy 64% / VALUBusy 63% -- block
// generations (10000 blocks retiring on their slowest wave) left 1/3 of
// SIMD slots idle. Persistent waves remove generation boundaries; degree
// variance averages over ~5 items/wave. Inner body verbatim from aggr4f
// (prepass-once alpha + LDS csr + fma_mix + elu_fast, R7-proven).
template <bool DOELU>
__global__ __launch_bounds__(256) void k_aggr4g(
    const unsigned short* __restrict__ h, const float* __restrict__ als,
    const float* __restrict__ ald,
    const int* __restrict__ off, const int* __restrict__ deg,
    const int* __restrict__ csr, const float* __restrict__ bias,
    unsigned short* __restrict__ outp, int N)
{
    __shared__ float alpS[4][64];     // [wave][edge-in-chunk], 1 KiB
    __shared__ int   csrS[4][64];     // pre-clamped sources, 1 KiB
    int wid = threadIdx.x >> 6;
    int lane = threadIdx.x & 63;
    int g = lane >> 4;                // edge group 0..3
    int p = lane & 15;                // channel-lane within group
    int nwaves = gridDim.x << 2;
    int items = N << 2;
    const char* hB = (const char*)h;

    for (int it = (blockIdx.x << 2) + wid; it < items; it += nwaves) {
        int head = it / N;            // head-major
        int n = it - head * N;
        int off0 = off[n];
        int degp = (deg[n] + 4) & ~3; // padded segment length
        float aldh = ald[n * 4 + head];
        const unsigned offp = (unsigned)(head * 256 + p * 16);

        float acc[8] = {};
        float den = 0.f;

        for (int base = 0; base < degp; base += 64) {
            // ---- prepass: one alpha per edge at this head; clamp csr once --
            float av = 0.f;
            int sc = 0;
            int e = base + lane;
            if (e < degp) {
                int s = csr[off0 + e];
                if (s >= 0) {
                    sc = s;
                    float l = als[(size_t)(unsigned)s * 4 + head] + aldh;
                    l = l > 0.f ? l : 0.2f * l;
                    av = __expf(l);
                }
            }
            alpS[wid][lane] = av;
            csrS[wid][lane] = sc;
            // single-wave LDS producer->consumer: DS pipe is in-order per wave

            // ---- quad loop: groups split the (up to) 16 quads of this chunk
            int qn = (degp - base) >> 2; if (qn > 16) qn = 16;
            for (int qq = g; qq < qn; qq += 4) {
                int4 cs = *(const int4*)&csrS[wid][qq * 4];
                f32x4 af = *(const f32x4*)&alpS[wid][qq * 4];
                uint4 h0 = *(const uint4*)(hB + (size_t)((((unsigned)cs.x) << 10) + offp));
                uint4 h1 = *(const uint4*)(hB + (size_t)((((unsigned)cs.y) << 10) + offp));
                uint4 h2 = *(const uint4*)(hB + (size_t)((((unsigned)cs.z) << 10) + offp));
                uint4 h3 = *(const uint4*)(hB + (size_t)((((unsigned)cs.w) << 10) + offp));
                den += (af[0] + af[1]) + (af[2] + af[3]);
                unsigned w0[4] = {h0.x, h0.y, h0.z, h0.w};
                unsigned w1[4] = {h1.x, h1.y, h1.z, h1.w};
                unsigned w2[4] = {h2.x, h2.y, h2.z, h2.w};
                unsigned w3[4] = {h3.x, h3.y, h3.z, h3.w};
#pragma unroll
                for (int wv = 0; wv < 4; ++wv) {
                    fma_mix_lo(acc[2 * wv],     af[0], w0[wv]);
                    fma_mix_hi(acc[2 * wv + 1], af[0], w0[wv]);
                }
#pragma unroll
                for (int wv = 0; wv < 4; ++wv) {
                    fma_mix_lo(acc[2 * wv],     af[1], w1[wv]);
                    fma_mix_hi(acc[2 * wv + 1], af[1], w1[wv]);
                }
#pragma unroll
                for (int wv = 0; wv < 4; ++wv) {
                    fma_mix_lo(acc[2 * wv],     af[2], w2[wv]);
                    fma_mix_hi(acc[2 * wv + 1], af[2], w2[wv]);
                }
#pragma unroll
                for (int wv = 0; wv < 4; ++wv) {
                    fma_mix_lo(acc[2 * wv],     af[3], w3[wv]);
                    fma_mix_hi(acc[2 * wv + 1], af[3], w3[wv]);
                }
            }
        }

        den += __shfl_xor(den, 16);
        den += __shfl_xor(den, 32);
#pragma unroll
        for (int j = 0; j < 8; ++j) {
            acc[j] += __shfl_xor(acc[j], 16);
            acc[j] += __shfl_xor(acc[j], 32);
        }

        if (g == 0) {
            float inv = 1.f / den;
            int cb = head * 128 + p * 8;
            unsigned ww[4];
#pragma unroll
            for (int wv = 0; wv < 4; ++wv) {
                float v0 = acc[2 * wv] * inv + bias[cb + 2 * wv];
                float v1 = acc[2 * wv + 1] * inv + bias[cb + 2 * wv + 1];
                if (DOELU) {
                    v0 = elu_fast(v0);
                    v1 = elu_fast(v1);
                }
                ww[wv] = (unsigned)f2h_bits(v0) | ((unsigned)f2h_bits(v1) << 16);
            }
            uint4 o; o.x = ww[0]; o.y = ww[1]; o.z = ww[2]; o.w = ww[3];
            *((uint4*)(outp + (size_t)n * 512 + cb)) = o;
        }
    }
}

// ---------------- layer-3 aggr (HC=64, H=1, fp16 h): prepass + LDS csr ----
// Non-persistent: 10000 items on 8192 waves would worsen balance.
__global__ __launch_bounds__(256) void k_aggr1c(
    const unsigned short* __restrict__ h, const float* __restrict__ als,
    const float* __restrict__ aldv, const int* __restrict__ off,
    const int* __restrict__ deg,
    const int* __restrict__ csr, const float* __restrict__ bias,
    float* __restrict__ outp, int N)
{
    __shared__ float alpS[4][64];
    __shared__ int   csrS[4][64];
    int wid = threadIdx.x >> 6;
    int n = blockIdx.x * 4 + wid;
    if (n >= N) return;
    int lane = threadIdx.x & 63;
    int g = lane >> 4;
    int p = lane & 15;

    int off0 = off[n];
    int degp = (deg[n] + 4) & ~3;
    float aldh = aldv[n];
    const char* hB = (const char*)h;
    const unsigned offp = (unsigned)(p * 8);   // bytes; lane owns 4 fp16 (8B)

    float acc[4] = {};
    float den = 0.f;

    for (int base = 0; base < degp; base += 64) {
        float av = 0.f;
        int sc = 0;
        int e = base + lane;
        if (e < degp) {
            int s = csr[off0 + e];
            if (s >= 0) {
                sc = s;
                float l = als[s] + aldh;
                l = l > 0.f ? l : 0.2f * l;
                av = __expf(l);
            }
        }
        alpS[wid][lane] = av;
        csrS[wid][lane] = sc;

        int qn = (degp - base) >> 2; if (qn > 16) qn = 16;
        for (int qq = g; qq < qn; qq += 4) {
            int4 cs = *(const int4*)&csrS[wid][qq * 4];
            f32x4 af = *(const f32x4*)&alpS[wid][qq * 4];
            uint2 h0 = *(const uint2*)(hB + (size_t)((((unsigned)cs.x) << 7) + offp));
            uint2 h1 = *(const uint2*)(hB + (size_t)((((unsigned)cs.y) << 7) + offp));
            uint2 h2 = *(const uint2*)(hB + (size_t)((((unsigned)cs.z) << 7) + offp));
            uint2 h3 = *(const uint2*)(hB + (size_t)((((unsigned)cs.w) << 7) + offp));
            den += (af[0] + af[1]) + (af[2] + af[3]);
            fma_mix_lo(acc[0], af[0], h0.x);
            fma_mix_hi(acc[1], af[0], h0.x);
            fma_mix_lo(acc[2], af[0], h0.y);
            fma_mix_hi(acc[3], af[0], h0.y);
            fma_mix_lo(acc[0], af[1], h1.x);
            fma_mix_hi(acc[1], af[1], h1.x);
            fma_mix_lo(acc[2], af[1], h1.y);
            fma_mix_hi(acc[3], af[1], h1.y);
            fma_mix_lo(acc[0], af[2], h2.x);
            fma_mix_hi(acc[1], af[2], h2.x);
            fma_mix_lo(acc[2], af[2], h2.y);
            fma_mix_hi(acc[3], af[2], h2.y);
            fma_mix_lo(acc[0], af[3], h3.x);
            fma_mix_hi(acc[1], af[3], h3.x);
            fma_mix_lo(acc[2], af[3], h3.y);
            fma_mix_hi(acc[3], af[3], h3.y);
        }
    }

    den += __shfl_xor(den, 16);
    den += __shfl_xor(den, 32);
#pragma unroll
    for (int j = 0; j < 4; ++j) {
        acc[j] += __shfl_xor(acc[j], 16);
        acc[j] += __shfl_xor(acc[j], 32);
    }
    if (g == 0) {
        float inv = 1.f / den;
        f32x4 o;
#pragma unroll
        for (int j = 0; j < 4; ++j)
            o[j] = acc[j] * inv + bias[p * 4 + j];
        *((f32x4*)(outp + (size_t)n * 64 + p * 4)) = o;
    }
}

// --------------------------------------------------------------------------
extern "C" void kernel_launch(void* const* d_in, const int* in_sizes, int n_in,
                              void* d_out, int out_size, void* d_ws, size_t ws_size,
                              hipStream_t stream)
{
    const float* x   = (const float*)d_in[0];
    const int*   ei  = (const int*)d_in[1];
    const float* W1  = (const float*)d_in[2];
    const float* as1 = (const float*)d_in[3];
    const float* ad1 = (const float*)d_in[4];
    const float* b1  = (const float*)d_in[5];
    const float* W2  = (const float*)d_in[6];
    const float* as2 = (const float*)d_in[7];
    const float* ad2 = (const float*)d_in[8];
    const float* b2  = (const float*)d_in[9];
    const float* W3  = (const float*)d_in[10];
    const float* as3 = (const float*)d_in[11];
    const float* ad3 = (const float*)d_in[12];
    const float* b3  = (const float*)d_in[13];

    const int DIN = 256, HC = 512, DOUT = 64;
    const int EXT = 64;                 // was/wad + zero-pad extension rows
    int N = in_sizes[0] / DIN;
    int E = in_sizes[1] / 2;
    int Mcap = E + 4 * N;  // capacity for 4-padded CSR

    // workspace carve-up
    char* w = (char*)d_ws;
    auto alloc = [&](size_t bytes) -> char* {
        char* p = w;
        w += (bytes + 255) & ~(size_t)255;
        return p;
    };
    // deg + tot first, contiguous -> ONE upfront memset
    int* deg    = (int*)alloc((size_t)N * 4);
    int* tot    = (int*)alloc(4);
    char* zend  = w;                       // end of zeroed span
    int* cur    = (int*)alloc((size_t)N * 4);
    int* off    = (int*)alloc((size_t)(N + 1) * 4);
    int* csr    = (int*)alloc((size_t)Mcap * 4);
    unsigned short* W1T = (unsigned short*)alloc((size_t)(HC + EXT) * DIN * 2);
    unsigned short* W2T = (unsigned short*)alloc((size_t)(HC + EXT) * HC * 2);
    unsigned short* W3T = (unsigned short*)alloc((size_t)DOUT * HC * 2);
    unsigned short* xb  = (unsigned short*)alloc((size_t)N * DIN * 2);
    unsigned short* act = (unsigned short*)alloc((size_t)N * HC * 2);
    unsigned short* hb  = (unsigned short*)alloc((size_t)N * HC * 2);
    unsigned short* hb3 = (unsigned short*)alloc((size_t)N * DOUT * 2);  // fp16 h (layer 3)
    float* als   = (float*)alloc((size_t)N * 4 * 4);
    float* ald   = (float*)alloc((size_t)N * 4 * 4);

    // ---- build: memset(deg+tot) -> prep(+was/wad, vectorized) -> alloc -> fill
    hipMemsetAsync(deg, 0, (size_t)(zend - (char*)deg), stream);
    int prep_total = DIN * HC + HC * HC + HC * DOUT + (N * DIN) / 4 + (Mcap + 3) / 4
                   + E + 8 * DIN + 8 * HC + 56 * DIN + 56 * HC;
    k_prep<<<(prep_total + 255) / 256, 256, 0, stream>>>(
        W1, W1T, W2, W2T, W3, W3T, x, xb, csr, Mcap, ei, E, deg,
        as1, ad1, as2, ad2, DIN, HC, DOUT, N);
    k_alloc<<<(N + 255) / 256, 256, 0, stream>>>(deg, off, cur, tot, N);
    k_fill<<<(E + N + 255) / 256, 256, 0, stream>>>(ei, E, N, cur, csr);

    int tiles_m = (N + 63) / 64;
    auto gemm_blocks = [&](int tn) { return (tiles_m * tn + 3) / 4; };
    int tm128 = (N + 127) / 128;
    int tiles_n12 = HC / 64 + 1;        // 8 data tiles + 1 al tile
    int nwave_blocks = (N + 3) / 4;
    const int AGGR_BLOCKS = 2048;       // 8 blocks/CU co-resident, persistent

    // ---- layer 1 ----
    k_gemm_lds<<<tm128 * tiles_n12, 256, 0, stream>>>(xb, W1T, hb, N, DIN, HC, tiles_n12, als, ald);
    k_aggr4g<true><<<AGGR_BLOCKS, 256, 0, stream>>>(hb, als, ald, off, deg, csr, b1, act, N);

    // ---- layer 2 ----
    k_gemm_lds<<<tm128 * tiles_n12, 256, 0, stream>>>(act, W2T, hb, N, HC, HC, tiles_n12, als, ald);
    k_aggr4g<true><<<AGGR_BLOCKS, 256, 0, stream>>>(hb, als, ald, off, deg, csr, b2, act, N);

    // ---- layer 3 (fp16 h path; Nc=64, al fused into GEMM epilogue) ----
    k_gemm<true, true><<<gemm_blocks(1), 256, 0, stream>>>(
        act, W3T, hb3, N, HC, DOUT, 1, as3, ad3, als, ald);
    k_aggr1c<<<nwave_blocks, 256, 0, stream>>>(hb3, als, ald, off, deg, csr, b3, (float*)d_out, N);
}

// Round 12
// 254.096 us; speedup vs baseline: 1.0094x; 1.0094x over previous
//
#include <hip/hip_runtime.h>
#include <hip/hip_fp16.h>

typedef _Float16 f16x8 __attribute__((ext_vector_type(8)));
typedef float f32x4 __attribute__((ext_vector_type(4)));

__device__ __forceinline__ unsigned short f2h_bits(float f) {
    __half h = __float2half(f);
    return *reinterpret_cast<unsigned short*>(&h);
}
__device__ __forceinline__ float h2f_bits(unsigned short u) {
    __half h = *reinterpret_cast<__half*>(&u);
    return __half2float(h);
}

// acc += a(f32) * f16_lo(hw)  -- one VOP3P v_fma_mix_f32
__device__ __forceinline__ void fma_mix_lo(float& acc, float a, unsigned hw) {
    asm("v_fma_mix_f32 %0, %1, %2, %0 op_sel_hi:[0,1,0]"
        : "+v"(acc) : "v"(a), "v"(hw));
}
// acc += a(f32) * f16_hi(hw)
__device__ __forceinline__ void fma_mix_hi(float& acc, float a, unsigned hw) {
    asm("v_fma_mix_f32 %0, %1, %2, %0 op_sel:[0,1,0] op_sel_hi:[0,1,0]"
        : "+v"(acc) : "v"(a), "v"(hw));
}

// fast ELU: x>0 ? x : e^x-1  (exp never NaN; select discards the inf branch)
__device__ __forceinline__ float elu_fast(float v) {
    float e = __expf(v) - 1.f;
    return v > 0.f ? v : e;
}

// async 16B global->LDS (DMA path, no VGPR round-trip). LDS dest is
// wave-uniform base + lane*16 (HW rule) -- layout below is linear in lane order.
__device__ __forceinline__ void gload_lds16(const void* g, void* l) {
    __builtin_amdgcn_global_load_lds(
        (const __attribute__((address_space(1))) unsigned int*)g,
        (__attribute__((address_space(3))) unsigned int*)l, 16, 0, 0);
}

// ---------------- prep: W transposes (fp16) + was/wad fold, x cvt, csr, deg --
// was[k,h] = sum_c W[k,128h+c]*a_src[h,c] (f32 math, fp16 store): attention
// logits become 8 extra GEMM columns (R8 structure). Vectorized (R11): x cvt
// via float4 (4 elems/thread), csr init via int4 -- prep threads 3.7M -> 1.5M.
// csr-init int4 tail may overrun into cur[] pad: harmless, k_alloc fully
// rewrites cur before any use. deg (+tot) zeroed by hipMemsetAsync.
__global__ void k_prep(const float* __restrict__ W1, unsigned short* __restrict__ W1T,
                       const float* __restrict__ W2, unsigned short* __restrict__ W2T,
                       const float* __restrict__ W3, unsigned short* __restrict__ W3T,
                       const float* __restrict__ x, unsigned short* __restrict__ xb,
                       int* __restrict__ csr, int Mcap,
                       const int* __restrict__ ei, int E, int* __restrict__ deg,
                       const float* __restrict__ as1, const float* __restrict__ ad1,
                       const float* __restrict__ as2, const float* __restrict__ ad2,
                       int DIN, int HC, int DOUT, int N)
{
    int i = blockIdx.x * blockDim.x + threadIdx.x;
    int n1 = DIN * HC;
    int n2 = n1 + HC * HC;
    int n3 = n2 + HC * DOUT;
    int n4 = n3 + ((N * DIN) >> 2);      // x cvt, float4 granularity
    int n5 = n4 + ((Mcap + 3) >> 2);     // csr init, int4 granularity
    int n6 = n5 + E;
    int n7 = n6 + 8 * DIN;               // was1/wad1
    int n8 = n7 + 8 * HC;                // was2/wad2
    int n9 = n8 + 56 * DIN + 56 * HC;    // zero pad rows 520..575
    if (i < n1) {
        int k = i / HC, n = i - k * HC;
        W1T[n * DIN + k] = f2h_bits(W1[i]);
    } else if (i < n2) {
        int j = i - n1;
        int k = j / HC, n = j - k * HC;
        W2T[n * HC + k] = f2h_bits(W2[j]);
    } else if (i < n3) {
        int j = i - n2;
        int k = j / DOUT, n = j - k * DOUT;
        W3T[n * HC + k] = f2h_bits(W3[j]);
    } else if (i < n4) {
        int j = i - n3;
        float4 v = *(const float4*)(x + 4 * (size_t)j);
        unsigned lo = (unsigned)f2h_bits(v.x) | ((unsigned)f2h_bits(v.y) << 16);
        unsigned hi = (unsigned)f2h_bits(v.z) | ((unsigned)f2h_bits(v.w) << 16);
        uint2 o; o.x = lo; o.y = hi;
        *(uint2*)(xb + 4 * (size_t)j) = o;
    } else if (i < n5) {
        int j = i - n4;
        int4 mm; mm.x = -1; mm.y = -1; mm.z = -1; mm.w = -1;
        *(int4*)(csr + 4 * (size_t)j) = mm;   // pad sentinel
    } else if (i < n6) {
        atomicAdd(&deg[ei[E + (i - n5)]], 1);
    } else if (i < n7) {
        int j = i - n6;
        int h8 = j / DIN, k = j - h8 * DIN;
        int hh = h8 & 3;
        const float* av = (h8 < 4 ? as1 : ad1) + hh * 128;
        const float* wr = W1 + (size_t)k * HC + hh * 128;
        float s = 0.f;
        for (int c = 0; c < 128; ++c) s += wr[c] * av[c];
        W1T[(size_t)(HC + h8) * DIN + k] = f2h_bits(s);
    } else if (i < n8) {
        int j = i - n7;
        int h8 = j / HC, k = j - h8 * HC;
        int hh = h8 & 3;
        const float* av = (h8 < 4 ? as2 : ad2) + hh * 128;
        const float* wr = W2 + (size_t)k * HC + hh * 128;
        float s = 0.f;
        for (int c = 0; c < 128; ++c) s += wr[c] * av[c];
        W2T[(size_t)(HC + h8) * HC + k] = f2h_bits(s);
    } else if (i < n9) {
        int j = i - n8;
        if (j < 56 * DIN) W1T[(size_t)(HC + 8) * DIN + j] = 0;
        else              W2T[(size_t)(HC + 8) * HC + (j - 56 * DIN)] = 0;
    }
}

// ---------------- parallel segment allocator ------------------------------
// Segment ORDER is irrelevant (aggr derives length from deg[n]); per-wave
// inclusive shfl-scan + ONE atomicAdd per wave assigns bases (R10: replaced
// the serial single-workgroup scan, -9us).
__global__ void k_alloc(const int* __restrict__ deg, int* __restrict__ off,
                        int* __restrict__ cur, int* __restrict__ tot, int N)
{
    int i = blockIdx.x * blockDim.x + threadIdx.x;
    int lane = threadIdx.x & 63;
    int sz = (i < N) ? ((deg[i] + 4) & ~3) : 0;
    int run = sz;
#pragma unroll
    for (int d = 1; d < 64; d <<= 1) {
        int v = __shfl_up(run, d);
        if (lane >= d) run += v;
    }
    int wtot = __shfl(run, 63);
    int base = 0;
    if (lane == 63) base = atomicAdd(tot, wtot);
    base = __shfl(base, 63);
    if (i < N) {
        int p = base + run - sz;   // exclusive within wave
        off[i] = p;
        cur[i] = p;
    }
}

__global__ void k_fill(const int* __restrict__ ei, int E, int N,
                       int* cur, int* __restrict__ csr) {
    int i = blockIdx.x * blockDim.x + threadIdx.x;
    if (i < E) {
        int s = ei[i], d = ei[E + i];
        int pos = atomicAdd(&cur[d], 1);
        csr[pos] = s;
    } else if (i < E + N) {
        int nn = i - E;
        int pos = atomicAdd(&cur[nn], 1);
        csr[pos] = nn;
    }
}

// ---------------- GEMM (layer 3 / small-Nc path): register-only 64x64, fp16 --
// DOAL: fused attention-logit epilogue (valid only when tiles_n==1, i.e. the
// wave's 64 cols are ALL output cols; layer 3, H=1). Per row:
// al_s[row] = sum_col acc*a_src -> 4 FMA + shfl_xor reduce over the 16 r-lanes.
template <bool OUTH, bool DOAL>
__global__ __launch_bounds__(256) void k_gemm(
    const unsigned short* __restrict__ A, const unsigned short* __restrict__ BT,
    void* __restrict__ D, int M, int K, int Nc, int tiles_n,
    const float* __restrict__ asrc, const float* __restrict__ adst,
    float* __restrict__ als, float* __restrict__ ald)
{
    int wid = blockIdx.x * (blockDim.x >> 6) + (threadIdx.x >> 6);
    int tiles_m = (M + 63) >> 6;
    if (wid >= tiles_m * tiles_n) return;
    int lane = threadIdx.x & 63;
    int tm = wid / tiles_n, tn = wid - tm * tiles_n;
    int m0 = tm << 6, n0 = tn << 6;
    int r = lane & 15, q = lane >> 4;

    const unsigned short* Arow[4];
    const unsigned short* Brow[4];
#pragma unroll
    for (int i = 0; i < 4; ++i) {
        int row = m0 + 16 * i + r; row = row < M ? row : M - 1;
        Arow[i] = A + (size_t)row * K + q * 8;
        Brow[i] = BT + (size_t)(n0 + 16 * i + r) * K + q * 8;
    }

    f32x4 acc[4][4] = {};
    f16x8 a[4], b[4], a2[4], b2[4];
#pragma unroll
    for (int i = 0; i < 4; ++i) {
        a[i] = *(const f16x8*)(Arow[i]);
        b[i] = *(const f16x8*)(Brow[i]);
    }
    for (int k0 = 0; k0 < K; k0 += 32) {
        int kn = k0 + 32;
        if (kn < K) {
#pragma unroll
            for (int i = 0; i < 4; ++i) {
                a2[i] = *(const f16x8*)(Arow[i] + kn);
                b2[i] = *(const f16x8*)(Brow[i] + kn);
            }
        }
#pragma unroll
        for (int i = 0; i < 4; ++i)
#pragma unroll
            for (int j = 0; j < 4; ++j)
                acc[i][j] = __builtin_amdgcn_mfma_f32_16x16x32_f16(a[i], b[j], acc[i][j], 0, 0, 0);
        if (kn < K) {
#pragma unroll
            for (int i = 0; i < 4; ++i) { a[i] = a2[i]; b[i] = b2[i]; }
        }
    }
#pragma unroll
    for (int i = 0; i < 4; ++i) {
        int rowb = m0 + 16 * i + q * 4;
#pragma unroll
        for (int rr = 0; rr < 4; ++rr) {
            int row = rowb + rr;
            if (row < M) {
#pragma unroll
                for (int j = 0; j < 4; ++j) {
                    int col = n0 + 16 * j + r;
                    if (OUTH)
                        ((unsigned short*)D)[(size_t)row * Nc + col] = f2h_bits(acc[i][j][rr]);
                    else
                        ((float*)D)[(size_t)row * Nc + col] = acc[i][j][rr];
                }
            }
        }
    }
    if (DOAL) {
        float asl[4], adl[4];
#pragma unroll
        for (int j = 0; j < 4; ++j) { asl[j] = asrc[16 * j + r]; adl[j] = adst[16 * j + r]; }
#pragma unroll
        for (int i = 0; i < 4; ++i) {
#pragma unroll
            for (int rr = 0; rr < 4; ++rr) {
                float s = 0.f, d = 0.f;
#pragma unroll
                for (int j = 0; j < 4; ++j) {
                    s += acc[i][j][rr] * asl[j];
                    d += acc[i][j][rr] * adl[j];
                }
#pragma unroll
                for (int dd = 1; dd < 16; dd <<= 1) {
                    s += __shfl_xor(s, dd);
                    d += __shfl_xor(d, dd);
                }
                int row = m0 + 16 * i + q * 4 + rr;
                if (r == 0 && row < M) { als[row] = s; ald[row] = d; }
            }
        }
    }
}

// ---------------- GEMM (layers 1&2): m97-style 128x64 tile, LDS-staged, fp16 --
// 4 waves (2x2), wave tile 64x32, BK=32. Staging via global_load_lds width 16.
// tiles_n = HC/64 + 1: the LAST column-tile multiplies the was/wad extension
// rows of BT (512..519; 520..575 zero), so its accumulators ARE the attention
// logits -- epilogue writes als/ald (f32, exclusive). R8-proven structure;
// R9's dbuf+atomics variant regressed (+30us) -- do not re-add.
__global__ __launch_bounds__(256) void k_gemm_lds(
    const unsigned short* __restrict__ A, const unsigned short* __restrict__ BT,
    unsigned short* __restrict__ D, int M, int K, int Nc, int tiles_n,
    float* __restrict__ als, float* __restrict__ ald)
{
    __shared__ unsigned short As[128 * 32];   // 8 KiB
    __shared__ unsigned short Bs[64 * 32];    // 4 KiB
    int tm = blockIdx.x / tiles_n, tn = blockIdx.x - tm * tiles_n;
    int m0 = tm << 7, n0 = tn << 6;
    int tid = threadIdx.x;
    int w = tid >> 6, lane = tid & 63;
    int wr = w >> 1, wc = w & 1;
    int r = lane & 15, q = lane >> 4;

    // staging: chunk c = 16 tile-rows; lane l -> row c*16 + l/4, bytes (l&3)*16
    int lrow = lane >> 2;
    int lch = (lane & 3) * 8;                  // in fp16 elements
    int ga0 = m0 + w * 16 + lrow;       if (ga0 >= M) ga0 = M - 1;
    int ga1 = m0 + (w + 4) * 16 + lrow; if (ga1 >= M) ga1 = M - 1;
    const unsigned short* pa0 = A + (size_t)ga0 * K + lch;
    const unsigned short* pa1 = A + (size_t)ga1 * K + lch;
    const unsigned short* pb  = BT + (size_t)(n0 + w * 16 + lrow) * K + lch;
    unsigned short* lA0 = As + w * 512;        // wave-uniform LDS chunk bases
    unsigned short* lA1 = As + (w + 4) * 512;
    unsigned short* lB  = Bs + w * 512;

    const unsigned short* arp = As + (wr * 64 + r) * 32 + q * 8;
    const unsigned short* brp = Bs + (wc * 32 + r) * 32 + q * 8;

    f32x4 acc[4][2] = {};
    for (int k0 = 0; k0 < K; k0 += 32) {
        gload_lds16(pa0 + k0, lA0);
        gload_lds16(pa1 + k0, lA1);
        gload_lds16(pb + k0, lB);
        __syncthreads();                        // compiler drains vmcnt(0) here
        f16x8 a[4], b[2];
#pragma unroll
        for (int i = 0; i < 4; ++i) a[i] = *(const f16x8*)(arp + i * 16 * 32);
#pragma unroll
        for (int j = 0; j < 2; ++j) b[j] = *(const f16x8*)(brp + j * 16 * 32);
#pragma unroll
        for (int i = 0; i < 4; ++i)
#pragma unroll
            for (int j = 0; j < 2; ++j)
                acc[i][j] = __builtin_amdgcn_mfma_f32_16x16x32_f16(a[i], b[j], acc[i][j], 0, 0, 0);
        __syncthreads();                        // protect LDS before next stage
    }
    if (tn == tiles_n - 1) {
        // al tile: col r (wc==0, j==0) maps to BT row 512+r: r<4 -> als head r,
        // r in 4..7 -> ald head r-4. Exclusive f32 writes, no atomics.
        if (wc == 0 && r < 8) {
            float* dst = (r < 4) ? als : ald;
            int hh = r & 3;
#pragma unroll
            for (int i = 0; i < 4; ++i)
#pragma unroll
                for (int rr = 0; rr < 4; ++rr) {
                    int row = m0 + wr * 64 + 16 * i + q * 4 + rr;
                    if (row < M) dst[row * 4 + hh] = acc[i][0][rr];
                }
        }
        return;
    }
#pragma unroll
    for (int i = 0; i < 4; ++i) {
        int rowb = m0 + wr * 64 + 16 * i + q * 4;
#pragma unroll
        for (int rr = 0; rr < 4; ++rr) {
            int row = rowb + rr;
            if (row < M) {
#pragma unroll
                for (int j = 0; j < 2; ++j) {
                    int col = n0 + wc * 32 + 16 * j + r;
                    D[(size_t)row * Nc + col] = f2h_bits(acc[i][j][rr]);
                }
            }
        }
    }
}

// ---------------- aggr HC=512 H=4: (node,head) slab, prepass, LDS csr ------
// NON-PERSISTENT (R12: persistent variant was +2-5us -- aggr stalls are
// per-item dependent latency, not generation-tail idleness). Wave =
// (node,head); head-major grid keeps each XCD's h-gather window to a 2.56MB
// head plane (L2-resident; R2: 86% L2 hit). Per 64-edge chunk: PREPASS
// computes alpha(e,head) once per edge and stages alpha + pre-clamped csr in
// LDS; QUAD loop reads int4 csr + f32x4 alpha via broadcast ds_read.
// Epilogue ELU via exp-1+select (R7: expm1f expansion was ~200 insts/wave).
// Segment length derived from deg[n] (off is an unordered allocation).
template <bool DOELU>
__global__ __launch_bounds__(256) void k_aggr4f(
    const unsigned short* __restrict__ h, const float* __restrict__ als,
    const float* __restrict__ ald,
    const int* __restrict__ off, const int* __restrict__ deg,
    const int* __restrict__ csr,
    const float* __restrict__ bias,
    unsigned short* __restrict__ outp, int N, int nodeBlocks)
{
    __shared__ float alpS[4][64];     // [wave][edge-in-chunk], 1 KiB
    __shared__ int   csrS[4][64];     // pre-clamped sources, 1 KiB
    int head = blockIdx.x / nodeBlocks;
    int nb = blockIdx.x - head * nodeBlocks;
    int wid = threadIdx.x >> 6;
    int n = nb * 4 + wid;
    if (n >= N) return;
    int lane = threadIdx.x & 63;
    int g = lane >> 4;                // edge group 0..3
    int p = lane & 15;                // channel-lane within group

    int off0 = off[n];
    int degp = (deg[n] + 4) & ~3;     // padded segment length
    float aldh = ald[n * 4 + head];
    const char* hB = (const char*)h;
    const unsigned offp = (unsigned)(head * 256 + p * 16);   // bytes within row

    float acc[8] = {};
    float den = 0.f;

    for (int base = 0; base < degp; base += 64) {
        // ---- prepass: one alpha per edge at this head; clamp csr once ----
        float av = 0.f;
        int sc = 0;
        int e = base + lane;
        if (e < degp) {
            int s = csr[off0 + e];
            if (s >= 0) {
                sc = s;
                float l = als[(size_t)(unsigned)s * 4 + head] + aldh;
                l = l > 0.f ? l : 0.2f * l;
                av = __expf(l);
            }
        }
        alpS[wid][lane] = av;
        csrS[wid][lane] = sc;
        // single-wave LDS producer->consumer: DS pipe is in-order per wave

        // ---- quad loop: groups split the (up to) 16 quads of this chunk ----
        int qn = (degp - base) >> 2; if (qn > 16) qn = 16;
        for (int qq = g; qq < qn; qq += 4) {
            int4 cs = *(const int4*)&csrS[wid][qq * 4];
            f32x4 af = *(const f32x4*)&alpS[wid][qq * 4];
            uint4 h0 = *(const uint4*)(hB + (size_t)((((unsigned)cs.x) << 10) + offp));
            uint4 h1 = *(const uint4*)(hB + (size_t)((((unsigned)cs.y) << 10) + offp));
            uint4 h2 = *(const uint4*)(hB + (size_t)((((unsigned)cs.z) << 10) + offp));
            uint4 h3 = *(const uint4*)(hB + (size_t)((((unsigned)cs.w) << 10) + offp));
            den += (af[0] + af[1]) + (af[2] + af[3]);
            unsigned w0[4] = {h0.x, h0.y, h0.z, h0.w};
            unsigned w1[4] = {h1.x, h1.y, h1.z, h1.w};
            unsigned w2[4] = {h2.x, h2.y, h2.z, h2.w};
            unsigned w3[4] = {h3.x, h3.y, h3.z, h3.w};
#pragma unroll
            for (int wv = 0; wv < 4; ++wv) {
                fma_mix_lo(acc[2 * wv],     af[0], w0[wv]);
                fma_mix_hi(acc[2 * wv + 1], af[0], w0[wv]);
            }
#pragma unroll
            for (int wv = 0; wv < 4; ++wv) {
                fma_mix_lo(acc[2 * wv],     af[1], w1[wv]);
                fma_mix_hi(acc[2 * wv + 1], af[1], w1[wv]);
            }
#pragma unroll
            for (int wv = 0; wv < 4; ++wv) {
                fma_mix_lo(acc[2 * wv],     af[2], w2[wv]);
                fma_mix_hi(acc[2 * wv + 1], af[2], w2[wv]);
            }
#pragma unroll
            for (int wv = 0; wv < 4; ++wv) {
                fma_mix_lo(acc[2 * wv],     af[3], w3[wv]);
                fma_mix_hi(acc[2 * wv + 1], af[3], w3[wv]);
            }
        }
    }

    den += __shfl_xor(den, 16);
    den += __shfl_xor(den, 32);
#pragma unroll
    for (int j = 0; j < 8; ++j) {
        acc[j] += __shfl_xor(acc[j], 16);
        acc[j] += __shfl_xor(acc[j], 32);
    }

    if (g == 0) {
        float inv = 1.f / den;
        int cb = head * 128 + p * 8;
        unsigned ww[4];
#pragma unroll
        for (int wv = 0; wv < 4; ++wv) {
            float v0 = acc[2 * wv] * inv + bias[cb + 2 * wv];
            float v1 = acc[2 * wv + 1] * inv + bias[cb + 2 * wv + 1];
            if (DOELU) {
                v0 = elu_fast(v0);
                v1 = elu_fast(v1);
            }
            ww[wv] = (unsigned)f2h_bits(v0) | ((unsigned)f2h_bits(v1) << 16);
        }
        uint4 o; o.x = ww[0]; o.y = ww[1]; o.z = ww[2]; o.w = ww[3];
        *((uint4*)(outp + (size_t)n * 512 + cb)) = o;
    }
}

// ---------------- layer-3 aggr (HC=64, H=1, fp16 h): prepass + LDS csr ----
__global__ __launch_bounds__(256) void k_aggr1c(
    const unsigned short* __restrict__ h, const float* __restrict__ als,
    const float* __restrict__ aldv, const int* __restrict__ off,
    const int* __restrict__ deg,
    const int* __restrict__ csr, const float* __restrict__ bias,
    float* __restrict__ outp, int N)
{
    __shared__ float alpS[4][64];
    __shared__ int   csrS[4][64];
    int wid = threadIdx.x >> 6;
    int n = blockIdx.x * 4 + wid;
    if (n >= N) return;
    int lane = threadIdx.x & 63;
    int g = lane >> 4;
    int p = lane & 15;

    int off0 = off[n];
    int degp = (deg[n] + 4) & ~3;
    float aldh = aldv[n];
    const char* hB = (const char*)h;
    const unsigned offp = (unsigned)(p * 8);   // bytes; lane owns 4 fp16 (8B)

    float acc[4] = {};
    float den = 0.f;

    for (int base = 0; base < degp; base += 64) {
        float av = 0.f;
        int sc = 0;
        int e = base + lane;
        if (e < degp) {
            int s = csr[off0 + e];
            if (s >= 0) {
                sc = s;
                float l = als[s] + aldh;
                l = l > 0.f ? l : 0.2f * l;
                av = __expf(l);
            }
        }
        alpS[wid][lane] = av;
        csrS[wid][lane] = sc;

        int qn = (degp - base) >> 2; if (qn > 16) qn = 16;
        for (int qq = g; qq < qn; qq += 4) {
            int4 cs = *(const int4*)&csrS[wid][qq * 4];
            f32x4 af = *(const f32x4*)&alpS[wid][qq * 4];
            uint2 h0 = *(const uint2*)(hB + (size_t)((((unsigned)cs.x) << 7) + offp));
            uint2 h1 = *(const uint2*)(hB + (size_t)((((unsigned)cs.y) << 7) + offp));
            uint2 h2 = *(const uint2*)(hB + (size_t)((((unsigned)cs.z) << 7) + offp));
            uint2 h3 = *(const uint2*)(hB + (size_t)((((unsigned)cs.w) << 7) + offp));
            den += (af[0] + af[1]) + (af[2] + af[3]);
            fma_mix_lo(acc[0], af[0], h0.x);
            fma_mix_hi(acc[1], af[0], h0.x);
            fma_mix_lo(acc[2], af[0], h0.y);
            fma_mix_hi(acc[3], af[0], h0.y);
            fma_mix_lo(acc[0], af[1], h1.x);
            fma_mix_hi(acc[1], af[1], h1.x);
            fma_mix_lo(acc[2], af[1], h1.y);
            fma_mix_hi(acc[3], af[1], h1.y);
            fma_mix_lo(acc[0], af[2], h2.x);
            fma_mix_hi(acc[1], af[2], h2.x);
            fma_mix_lo(acc[2], af[2], h2.y);
            fma_mix_hi(acc[3], af[2], h2.y);
            fma_mix_lo(acc[0], af[3], h3.x);
            fma_mix_hi(acc[1], af[3], h3.x);
            fma_mix_lo(acc[2], af[3], h3.y);
            fma_mix_hi(acc[3], af[3], h3.y);
        }
    }

    den += __shfl_xor(den, 16);
    den += __shfl_xor(den, 32);
#pragma unroll
    for (int j = 0; j < 4; ++j) {
        acc[j] += __shfl_xor(acc[j], 16);
        acc[j] += __shfl_xor(acc[j], 32);
    }
    if (g == 0) {
        float inv = 1.f / den;
        f32x4 o;
#pragma unroll
        for (int j = 0; j < 4; ++j)
            o[j] = acc[j] * inv + bias[p * 4 + j];
        *((f32x4*)(outp + (size_t)n * 64 + p * 4)) = o;
    }
}

// --------------------------------------------------------------------------
extern "C" void kernel_launch(void* const* d_in, const int* in_sizes, int n_in,
                              void* d_out, int out_size, void* d_ws, size_t ws_size,
                              hipStream_t stream)
{
    const float* x   = (const float*)d_in[0];
    const int*   ei  = (const int*)d_in[1];
    const float* W1  = (const float*)d_in[2];
    const float* as1 = (const float*)d_in[3];
    const float* ad1 = (const float*)d_in[4];
    const float* b1  = (const float*)d_in[5];
    const float* W2  = (const float*)d_in[6];
    const float* as2 = (const float*)d_in[7];
    const float* ad2 = (const float*)d_in[8];
    const float* b2  = (const float*)d_in[9];
    const float* W3  = (const float*)d_in[10];
    const float* as3 = (const float*)d_in[11];
    const float* ad3 = (const float*)d_in[12];
    const float* b3  = (const float*)d_in[13];

    const int DIN = 256, HC = 512, DOUT = 64;
    const int EXT = 64;                 // was/wad + zero-pad extension rows
    int N = in_sizes[0] / DIN;
    int E = in_sizes[1] / 2;
    int Mcap = E + 4 * N;  // capacity for 4-padded CSR

    // workspace carve-up
    char* w = (char*)d_ws;
    auto alloc = [&](size_t bytes) -> char* {
        char* p = w;
        w += (bytes + 255) & ~(size_t)255;
        return p;
    };
    // deg + tot first, contiguous -> ONE upfront memset
    int* deg    = (int*)alloc((size_t)N * 4);
    int* tot    = (int*)alloc(4);
    char* zend  = w;                       // end of zeroed span
    int* cur    = (int*)alloc((size_t)N * 4);
    int* off    = (int*)alloc((size_t)(N + 1) * 4);
    int* csr    = (int*)alloc((size_t)Mcap * 4);
    unsigned short* W1T = (unsigned short*)alloc((size_t)(HC + EXT) * DIN * 2);
    unsigned short* W2T = (unsigned short*)alloc((size_t)(HC + EXT) * HC * 2);
    unsigned short* W3T = (unsigned short*)alloc((size_t)DOUT * HC * 2);
    unsigned short* xb  = (unsigned short*)alloc((size_t)N * DIN * 2);
    unsigned short* act = (unsigned short*)alloc((size_t)N * HC * 2);
    unsigned short* hb  = (unsigned short*)alloc((size_t)N * HC * 2);
    unsigned short* hb3 = (unsigned short*)alloc((size_t)N * DOUT * 2);  // fp16 h (layer 3)
    float* als   = (float*)alloc((size_t)N * 4 * 4);
    float* ald   = (float*)alloc((size_t)N * 4 * 4);

    // ---- build: memset(deg+tot) -> prep(+was/wad, vectorized) -> alloc -> fill
    hipMemsetAsync(deg, 0, (size_t)(zend - (char*)deg), stream);
    int prep_total = DIN * HC + HC * HC + HC * DOUT + (N * DIN) / 4 + (Mcap + 3) / 4
                   + E + 8 * DIN + 8 * HC + 56 * DIN + 56 * HC;
    k_prep<<<(prep_total + 255) / 256, 256, 0, stream>>>(
        W1, W1T, W2, W2T, W3, W3T, x, xb, csr, Mcap, ei, E, deg,
        as1, ad1, as2, ad2, DIN, HC, DOUT, N);
    k_alloc<<<(N + 255) / 256, 256, 0, stream>>>(deg, off, cur, tot, N);
    k_fill<<<(E + N + 255) / 256, 256, 0, stream>>>(ei, E, N, cur, csr);

    int tiles_m = (N + 63) / 64;
    auto gemm_blocks = [&](int tn) { return (tiles_m * tn + 3) / 4; };
    int tm128 = (N + 127) / 128;
    int tiles_n12 = HC / 64 + 1;        // 8 data tiles + 1 al tile
    int nwave_blocks = (N + 3) / 4;
    int nodeBlocks = (N + 3) / 4;

    // ---- layer 1 ----
    k_gemm_lds<<<tm128 * tiles_n12, 256, 0, stream>>>(xb, W1T, hb, N, DIN, HC, tiles_n12, als, ald);
    k_aggr4f<true><<<4 * nodeBlocks, 256, 0, stream>>>(hb, als, ald, off, deg, csr, b1, act, N, nodeBlocks);

    // ---- layer 2 ----
    k_gemm_lds<<<tm128 * tiles_n12, 256, 0, stream>>>(act, W2T, hb, N, HC, HC, tiles_n12, als, ald);
    k_aggr4f<true><<<4 * nodeBlocks, 256, 0, stream>>>(hb, als, ald, off, deg, csr, b2, act, N, nodeBlocks);

    // ---- layer 3 (fp16 h path; Nc=64, al fused into GEMM epilogue) ----
    k_gemm<true, true><<<gemm_blocks(1), 256, 0, stream>>>(
        act, W3T, hb3, N, HC, DOUT, 1, as3, ad3, als, ald);
    k_aggr1c<<<nwave_blocks, 256, 0, stream>>>(hb3, als, ald, off, deg, csr, b3, (float*)d_out, N);
}

// Round 13
// 253.253 us; speedup vs baseline: 1.0128x; 1.0033x over previous
//
#include <hip/hip_runtime.h>
#include <hip/hip_fp16.h>

typedef _Float16 f16x8 __attribute__((ext_vector_type(8)));
typedef float f32x4 __attribute__((ext_vector_type(4)));

__device__ __forceinline__ unsigned short f2h_bits(float f) {
    __half h = __float2half(f);
    return *reinterpret_cast<unsigned short*>(&h);
}
__device__ __forceinline__ float h2f_bits(unsigned short u) {
    __half h = *reinterpret_cast<__half*>(&u);
    return __half2float(h);
}

// acc += a(f32) * f16_lo(hw)  -- one VOP3P v_fma_mix_f32
__device__ __forceinline__ void fma_mix_lo(float& acc, float a, unsigned hw) {
    asm("v_fma_mix_f32 %0, %1, %2, %0 op_sel_hi:[0,1,0]"
        : "+v"(acc) : "v"(a), "v"(hw));
}
// acc += a(f32) * f16_hi(hw)
__device__ __forceinline__ void fma_mix_hi(float& acc, float a, unsigned hw) {
    asm("v_fma_mix_f32 %0, %1, %2, %0 op_sel:[0,1,0] op_sel_hi:[0,1,0]"
        : "+v"(acc) : "v"(a), "v"(hw));
}

// fast ELU: x>0 ? x : e^x-1  (exp never NaN; select discards the inf branch)
__device__ __forceinline__ float elu_fast(float v) {
    float e = __expf(v) - 1.f;
    return v > 0.f ? v : e;
}

// async 16B global->LDS (DMA path, no VGPR round-trip). LDS dest is
// wave-uniform base + lane*16 (HW rule) -- layout below is linear in lane order.
__device__ __forceinline__ void gload_lds16(const void* g, void* l) {
    __builtin_amdgcn_global_load_lds(
        (const __attribute__((address_space(1))) unsigned int*)g,
        (__attribute__((address_space(3))) unsigned int*)l, 16, 0, 0);
}

// ---------------- prep: W transposes (fp16) + was/wad fold, x cvt, csr, deg --
// was[k,h] = sum_c W[k,128h+c]*a_src[h,c] (f32 math, fp16 store): attention
// logits become 8 extra GEMM columns (R8 structure). Vectorized (R11): x cvt
// via float4 (4 elems/thread), csr init via int4. csr-init int4 tail may
// overrun into cur[] pad: harmless, k_alloc fully rewrites cur before use.
// deg (+tot) zeroed by hipMemsetAsync.
__global__ void k_prep(const float* __restrict__ W1, unsigned short* __restrict__ W1T,
                       const float* __restrict__ W2, unsigned short* __restrict__ W2T,
                       const float* __restrict__ W3, unsigned short* __restrict__ W3T,
                       const float* __restrict__ x, unsigned short* __restrict__ xb,
                       int* __restrict__ csr, int Mcap,
                       const int* __restrict__ ei, int E, int* __restrict__ deg,
                       const float* __restrict__ as1, const float* __restrict__ ad1,
                       const float* __restrict__ as2, const float* __restrict__ ad2,
                       int DIN, int HC, int DOUT, int N)
{
    int i = blockIdx.x * blockDim.x + threadIdx.x;
    int n1 = DIN * HC;
    int n2 = n1 + HC * HC;
    int n3 = n2 + HC * DOUT;
    int n4 = n3 + ((N * DIN) >> 2);      // x cvt, float4 granularity
    int n5 = n4 + ((Mcap + 3) >> 2);     // csr init, int4 granularity
    int n6 = n5 + E;
    int n7 = n6 + 8 * DIN;               // was1/wad1
    int n8 = n7 + 8 * HC;                // was2/wad2
    int n9 = n8 + 56 * DIN + 56 * HC;    // zero pad rows 520..575
    if (i < n1) {
        int k = i / HC, n = i - k * HC;
        W1T[n * DIN + k] = f2h_bits(W1[i]);
    } else if (i < n2) {
        int j = i - n1;
        int k = j / HC, n = j - k * HC;
        W2T[n * HC + k] = f2h_bits(W2[j]);
    } else if (i < n3) {
        int j = i - n2;
        int k = j / DOUT, n = j - k * DOUT;
        W3T[n * HC + k] = f2h_bits(W3[j]);
    } else if (i < n4) {
        int j = i - n3;
        float4 v = *(const float4*)(x + 4 * (size_t)j);
        unsigned lo = (unsigned)f2h_bits(v.x) | ((unsigned)f2h_bits(v.y) << 16);
        unsigned hi = (unsigned)f2h_bits(v.z) | ((unsigned)f2h_bits(v.w) << 16);
        uint2 o; o.x = lo; o.y = hi;
        *(uint2*)(xb + 4 * (size_t)j) = o;
    } else if (i < n5) {
        int j = i - n4;
        int4 mm; mm.x = -1; mm.y = -1; mm.z = -1; mm.w = -1;
        *(int4*)(csr + 4 * (size_t)j) = mm;   // pad sentinel
    } else if (i < n6) {
        atomicAdd(&deg[ei[E + (i - n5)]], 1);
    } else if (i < n7) {
        int j = i - n6;
        int h8 = j / DIN, k = j - h8 * DIN;
        int hh = h8 & 3;
        const float* av = (h8 < 4 ? as1 : ad1) + hh * 128;
        const float* wr = W1 + (size_t)k * HC + hh * 128;
        float s = 0.f;
        for (int c = 0; c < 128; ++c) s += wr[c] * av[c];
        W1T[(size_t)(HC + h8) * DIN + k] = f2h_bits(s);
    } else if (i < n8) {
        int j = i - n7;
        int h8 = j / HC, k = j - h8 * HC;
        int hh = h8 & 3;
        const float* av = (h8 < 4 ? as2 : ad2) + hh * 128;
        const float* wr = W2 + (size_t)k * HC + hh * 128;
        float s = 0.f;
        for (int c = 0; c < 128; ++c) s += wr[c] * av[c];
        W2T[(size_t)(HC + h8) * HC + k] = f2h_bits(s);
    } else if (i < n9) {
        int j = i - n8;
        if (j < 56 * DIN) W1T[(size_t)(HC + 8) * DIN + j] = 0;
        else              W2T[(size_t)(HC + 8) * HC + (j - 56 * DIN)] = 0;
    }
}

// ---------------- parallel segment allocator ------------------------------
// Segment ORDER is irrelevant (aggr derives length from deg[n]); per-wave
// inclusive shfl-scan + ONE atomicAdd per wave assigns bases (R10, -9us).
__global__ void k_alloc(const int* __restrict__ deg, int* __restrict__ off,
                        int* __restrict__ cur, int* __restrict__ tot, int N)
{
    int i = blockIdx.x * blockDim.x + threadIdx.x;
    int lane = threadIdx.x & 63;
    int sz = (i < N) ? ((deg[i] + 4) & ~3) : 0;
    int run = sz;
#pragma unroll
    for (int d = 1; d < 64; d <<= 1) {
        int v = __shfl_up(run, d);
        if (lane >= d) run += v;
    }
    int wtot = __shfl(run, 63);
    int base = 0;
    if (lane == 63) base = atomicAdd(tot, wtot);
    base = __shfl(base, 63);
    if (i < N) {
        int p = base + run - sz;   // exclusive within wave
        off[i] = p;
        cur[i] = p;
    }
}

__global__ void k_fill(const int* __restrict__ ei, int E, int N,
                       int* cur, int* __restrict__ csr) {
    int i = blockIdx.x * blockDim.x + threadIdx.x;
    if (i < E) {
        int s = ei[i], d = ei[E + i];
        int pos = atomicAdd(&cur[d], 1);
        csr[pos] = s;
    } else if (i < E + N) {
        int nn = i - E;
        int pos = atomicAdd(&cur[nn], 1);
        csr[pos] = nn;
    }
}

// ---------------- GEMM (layer 3 / small-Nc path): register-only 64x64, fp16 --
// DOAL: fused attention-logit epilogue (valid only when tiles_n==1, i.e. the
// wave's 64 cols are ALL output cols; layer 3, H=1). Per row:
// al_s[row] = sum_col acc*a_src -> 4 FMA + shfl_xor reduce over the 16 r-lanes.
template <bool OUTH, bool DOAL>
__global__ __launch_bounds__(256) void k_gemm(
    const unsigned short* __restrict__ A, const unsigned short* __restrict__ BT,
    void* __restrict__ D, int M, int K, int Nc, int tiles_n,
    const float* __restrict__ asrc, const float* __restrict__ adst,
    float* __restrict__ als, float* __restrict__ ald)
{
    int wid = blockIdx.x * (blockDim.x >> 6) + (threadIdx.x >> 6);
    int tiles_m = (M + 63) >> 6;
    if (wid >= tiles_m * tiles_n) return;
    int lane = threadIdx.x & 63;
    int tm = wid / tiles_n, tn = wid - tm * tiles_n;
    int m0 = tm << 6, n0 = tn << 6;
    int r = lane & 15, q = lane >> 4;

    const unsigned short* Arow[4];
    const unsigned short* Brow[4];
#pragma unroll
    for (int i = 0; i < 4; ++i) {
        int row = m0 + 16 * i + r; row = row < M ? row : M - 1;
        Arow[i] = A + (size_t)row * K + q * 8;
        Brow[i] = BT + (size_t)(n0 + 16 * i + r) * K + q * 8;
    }

    f32x4 acc[4][4] = {};
    f16x8 a[4], b[4], a2[4], b2[4];
#pragma unroll
    for (int i = 0; i < 4; ++i) {
        a[i] = *(const f16x8*)(Arow[i]);
        b[i] = *(const f16x8*)(Brow[i]);
    }
    for (int k0 = 0; k0 < K; k0 += 32) {
        int kn = k0 + 32;
        if (kn < K) {
#pragma unroll
            for (int i = 0; i < 4; ++i) {
                a2[i] = *(const f16x8*)(Arow[i] + kn);
                b2[i] = *(const f16x8*)(Brow[i] + kn);
            }
        }
#pragma unroll
        for (int i = 0; i < 4; ++i)
#pragma unroll
            for (int j = 0; j < 4; ++j)
                acc[i][j] = __builtin_amdgcn_mfma_f32_16x16x32_f16(a[i], b[j], acc[i][j], 0, 0, 0);
        if (kn < K) {
#pragma unroll
            for (int i = 0; i < 4; ++i) { a[i] = a2[i]; b[i] = b2[i]; }
        }
    }
#pragma unroll
    for (int i = 0; i < 4; ++i) {
        int rowb = m0 + 16 * i + q * 4;
#pragma unroll
        for (int rr = 0; rr < 4; ++rr) {
            int row = rowb + rr;
            if (row < M) {
#pragma unroll
                for (int j = 0; j < 4; ++j) {
                    int col = n0 + 16 * j + r;
                    if (OUTH)
                        ((unsigned short*)D)[(size_t)row * Nc + col] = f2h_bits(acc[i][j][rr]);
                    else
                        ((float*)D)[(size_t)row * Nc + col] = acc[i][j][rr];
                }
            }
        }
    }
    if (DOAL) {
        float asl[4], adl[4];
#pragma unroll
        for (int j = 0; j < 4; ++j) { asl[j] = asrc[16 * j + r]; adl[j] = adst[16 * j + r]; }
#pragma unroll
        for (int i = 0; i < 4; ++i) {
#pragma unroll
            for (int rr = 0; rr < 4; ++rr) {
                float s = 0.f, d = 0.f;
#pragma unroll
                for (int j = 0; j < 4; ++j) {
                    s += acc[i][j][rr] * asl[j];
                    d += acc[i][j][rr] * adl[j];
                }
#pragma unroll
                for (int dd = 1; dd < 16; dd <<= 1) {
                    s += __shfl_xor(s, dd);
                    d += __shfl_xor(d, dd);
                }
                int row = m0 + 16 * i + q * 4 + rr;
                if (r == 0 && row < M) { als[row] = s; ald[row] = d; }
            }
        }
    }
}

// ---------------- GEMM (layers 1&2): 128x64 tile, BK=64, LDS-staged, fp16 ---
// R13: BK 32 -> 64. Same 2-barrier schedule (R9's dbuf regressed; this is a
// pure parameter change), but HALF the barrier steps: the drain+barrier is
// the dominant cost of this structure (m233: ~72%), so step count is the
// lever. Per step each wave DMAs 6 KiB (4 A chunks + 2 B chunks, 1 KiB
// gloads, linear lane order: chunk = 8 rows x 64 cols, lane l -> row l/8,
// 16B slot l&7) and runs 16 MFMAs (2 K-slices). LDS 24 KiB static. 16-way
// ds_read bank conflict from the 128B row stride is HIDDEN in this regime
// (T2 gate, m252: 2-phase critical path is stage+barrier, not LDS-read).
// tiles_n = HC/64 + 1: LAST column-tile multiplies the was/wad extension
// rows (512..575) -> its accumulators ARE the attention logits; epilogue
// writes als/ald (f32, exclusive).
__global__ __launch_bounds__(256) void k_gemm_lds(
    const unsigned short* __restrict__ A, const unsigned short* __restrict__ BT,
    unsigned short* __restrict__ D, int M, int K, int Nc, int tiles_n,
    float* __restrict__ als, float* __restrict__ ald)
{
    __shared__ unsigned short As[128 * 64];   // 16 KiB
    __shared__ unsigned short Bs[64 * 64];    // 8 KiB
    int tm = blockIdx.x / tiles_n, tn = blockIdx.x - tm * tiles_n;
    int m0 = tm << 7, n0 = tn << 6;
    int tid = threadIdx.x;
    int w = tid >> 6, lane = tid & 63;
    int wr = w >> 1, wc = w & 1;
    int r = lane & 15, q = lane >> 4;

    // staging: chunk = 8 rows x 64 cols (1 KiB); lane l -> row l>>3, slot l&7
    int lrow = lane >> 3;
    int lch = (lane & 7) * 8;                  // fp16 elems within row
    const unsigned short* pa[4];
    unsigned short* la[4];
#pragma unroll
    for (int c = 0; c < 4; ++c) {
        int ch = w * 4 + c;                    // A chunks 0..15
        int ga = m0 + ch * 8 + lrow; if (ga >= M) ga = M - 1;
        pa[c] = A + (size_t)ga * K + lch;
        la[c] = As + ch * 512;                 // wave-uniform LDS base
    }
    const unsigned short* pb[2];
    unsigned short* lb[2];
#pragma unroll
    for (int c = 0; c < 2; ++c) {
        int ch = w * 2 + c;                    // B chunks 0..7
        pb[c] = BT + (size_t)(n0 + ch * 8 + lrow) * K + lch;
        lb[c] = Bs + ch * 512;
    }

    const unsigned short* arp = As + (wr * 64 + r) * 64 + q * 8;
    const unsigned short* brp = Bs + (wc * 32 + r) * 64 + q * 8;

    f32x4 acc[4][2] = {};
    for (int k0 = 0; k0 < K; k0 += 64) {
#pragma unroll
        for (int c = 0; c < 4; ++c) gload_lds16(pa[c] + k0, la[c]);
#pragma unroll
        for (int c = 0; c < 2; ++c) gload_lds16(pb[c] + k0, lb[c]);
        __syncthreads();                        // compiler drains vmcnt(0) here
#pragma unroll
        for (int ks = 0; ks < 2; ++ks) {
            f16x8 a[4], b[2];
#pragma unroll
            for (int i = 0; i < 4; ++i) a[i] = *(const f16x8*)(arp + i * 16 * 64 + ks * 32);
#pragma unroll
            for (int j = 0; j < 2; ++j) b[j] = *(const f16x8*)(brp + j * 16 * 64 + ks * 32);
#pragma unroll
            for (int i = 0; i < 4; ++i)
#pragma unroll
                for (int j = 0; j < 2; ++j)
                    acc[i][j] = __builtin_amdgcn_mfma_f32_16x16x32_f16(a[i], b[j], acc[i][j], 0, 0, 0);
        }
        __syncthreads();                        // protect LDS before next stage
    }
    if (tn == tiles_n - 1) {
        // al tile: col r (wc==0, j==0) maps to BT row 512+r: r<4 -> als head r,
        // r in 4..7 -> ald head r-4. Exclusive f32 writes, no atomics.
        if (wc == 0 && r < 8) {
            float* dst = (r < 4) ? als : ald;
            int hh = r & 3;
#pragma unroll
            for (int i = 0; i < 4; ++i)
#pragma unroll
                for (int rr = 0; rr < 4; ++rr) {
                    int row = m0 + wr * 64 + 16 * i + q * 4 + rr;
                    if (row < M) dst[row * 4 + hh] = acc[i][0][rr];
                }
        }
        return;
    }
#pragma unroll
    for (int i = 0; i < 4; ++i) {
        int rowb = m0 + wr * 64 + 16 * i + q * 4;
#pragma unroll
        for (int rr = 0; rr < 4; ++rr) {
            int row = rowb + rr;
            if (row < M) {
#pragma unroll
                for (int j = 0; j < 2; ++j) {
                    int col = n0 + wc * 32 + 16 * j + r;
                    D[(size_t)row * Nc + col] = f2h_bits(acc[i][j][rr]);
                }
            }
        }
    }
}

// ---------------- aggr HC=512 H=4: (node,head) slab, prepass, LDS csr ------
// NON-PERSISTENT (R12 isolation: persistent variant regressed -- aggr stalls
// are per-item dependent latency, not generation-tail idleness). Wave =
// (node,head); head-major grid keeps each XCD's h-gather window to a 2.56MB
// head plane (L2-resident; R2: 86% L2 hit). Per 64-edge chunk: PREPASS
// computes alpha(e,head) once per edge and stages alpha + pre-clamped csr in
// LDS; QUAD loop reads int4 csr + f32x4 alpha via broadcast ds_read.
// Epilogue ELU via exp-1+select (R7: expm1f expansion was ~200 insts/wave).
// Segment length derived from deg[n] (off is an unordered allocation).
template <bool DOELU>
__global__ __launch_bounds__(256) void k_aggr4f(
    const unsigned short* __restrict__ h, const float* __restrict__ als,
    const float* __restrict__ ald,
    const int* __restrict__ off, const int* __restrict__ deg,
    const int* __restrict__ csr,
    const float* __restrict__ bias,
    unsigned short* __restrict__ outp, int N, int nodeBlocks)
{
    __shared__ float alpS[4][64];     // [wave][edge-in-chunk], 1 KiB
    __shared__ int   csrS[4][64];     // pre-clamped sources, 1 KiB
    int head = blockIdx.x / nodeBlocks;
    int nb = blockIdx.x - head * nodeBlocks;
    int wid = threadIdx.x >> 6;
    int n = nb * 4 + wid;
    if (n >= N) return;
    int lane = threadIdx.x & 63;
    int g = lane >> 4;                // edge group 0..3
    int p = lane & 15;                // channel-lane within group

    int off0 = off[n];
    int degp = (deg[n] + 4) & ~3;     // padded segment length
    float aldh = ald[n * 4 + head];
    const char* hB = (const char*)h;
    const unsigned offp = (unsigned)(head * 256 + p * 16);   // bytes within row

    float acc[8] = {};
    float den = 0.f;

    for (int base = 0; base < degp; base += 64) {
        // ---- prepass: one alpha per edge at this head; clamp csr once ----
        float av = 0.f;
        int sc = 0;
        int e = base + lane;
        if (e < degp) {
            int s = csr[off0 + e];
            if (s >= 0) {
                sc = s;
                float l = als[(size_t)(unsigned)s * 4 + head] + aldh;
                l = l > 0.f ? l : 0.2f * l;
                av = __expf(l);
            }
        }
        alpS[wid][lane] = av;
        csrS[wid][lane] = sc;
        // single-wave LDS producer->consumer: DS pipe is in-order per wave

        // ---- quad loop: groups split the (up to) 16 quads of this chunk ----
        int qn = (degp - base) >> 2; if (qn > 16) qn = 16;
        for (int qq = g; qq < qn; qq += 4) {
            int4 cs = *(const int4*)&csrS[wid][qq * 4];
            f32x4 af = *(const f32x4*)&alpS[wid][qq * 4];
            uint4 h0 = *(const uint4*)(hB + (size_t)((((unsigned)cs.x) << 10) + offp));
            uint4 h1 = *(const uint4*)(hB + (size_t)((((unsigned)cs.y) << 10) + offp));
            uint4 h2 = *(const uint4*)(hB + (size_t)((((unsigned)cs.z) << 10) + offp));
            uint4 h3 = *(const uint4*)(hB + (size_t)((((unsigned)cs.w) << 10) + offp));
            den += (af[0] + af[1]) + (af[2] + af[3]);
            unsigned w0[4] = {h0.x, h0.y, h0.z, h0.w};
            unsigned w1[4] = {h1.x, h1.y, h1.z, h1.w};
            unsigned w2[4] = {h2.x, h2.y, h2.z, h2.w};
            unsigned w3[4] = {h3.x, h3.y, h3.z, h3.w};
#pragma unroll
            for (int wv = 0; wv < 4; ++wv) {
                fma_mix_lo(acc[2 * wv],     af[0], w0[wv]);
                fma_mix_hi(acc[2 * wv + 1], af[0], w0[wv]);
            }
#pragma unroll
            for (int wv = 0; wv < 4; ++wv) {
                fma_mix_lo(acc[2 * wv],     af[1], w1[wv]);
                fma_mix_hi(acc[2 * wv + 1], af[1], w1[wv]);
            }
#pragma unroll
            for (int wv = 0; wv < 4; ++wv) {
                fma_mix_lo(acc[2 * wv],     af[2], w2[wv]);
                fma_mix_hi(acc[2 * wv + 1], af[2], w2[wv]);
            }
#pragma unroll
            for (int wv = 0; wv < 4; ++wv) {
                fma_mix_lo(acc[2 * wv],     af[3], w3[wv]);
                fma_mix_hi(acc[2 * wv + 1], af[3], w3[wv]);
            }
        }
    }

    den += __shfl_xor(den, 16);
    den += __shfl_xor(den, 32);
#pragma unroll
    for (int j = 0; j < 8; ++j) {
        acc[j] += __shfl_xor(acc[j], 16);
        acc[j] += __shfl_xor(acc[j], 32);
    }

    if (g == 0) {
        float inv = 1.f / den;
        int cb = head * 128 + p * 8;
        unsigned ww[4];
#pragma unroll
        for (int wv = 0; wv < 4; ++wv) {
            float v0 = acc[2 * wv] * inv + bias[cb + 2 * wv];
            float v1 = acc[2 * wv + 1] * inv + bias[cb + 2 * wv + 1];
            if (DOELU) {
                v0 = elu_fast(v0);
                v1 = elu_fast(v1);
            }
            ww[wv] = (unsigned)f2h_bits(v0) | ((unsigned)f2h_bits(v1) << 16);
        }
        uint4 o; o.x = ww[0]; o.y = ww[1]; o.z = ww[2]; o.w = ww[3];
        *((uint4*)(outp + (size_t)n * 512 + cb)) = o;
    }
}

// ---------------- layer-3 aggr (HC=64, H=1, fp16 h): prepass + LDS csr ----
__global__ __launch_bounds__(256) void k_aggr1c(
    const unsigned short* __restrict__ h, const float* __restrict__ als,
    const float* __restrict__ aldv, const int* __restrict__ off,
    const int* __restrict__ deg,
    const int* __restrict__ csr, const float* __restrict__ bias,
    float* __restrict__ outp, int N)
{
    __shared__ float alpS[4][64];
    __shared__ int   csrS[4][64];
    int wid = threadIdx.x >> 6;
    int n = blockIdx.x * 4 + wid;
    if (n >= N) return;
    int lane = threadIdx.x & 63;
    int g = lane >> 4;
    int p = lane & 15;

    int off0 = off[n];
    int degp = (deg[n] + 4) & ~3;
    float aldh = aldv[n];
    const char* hB = (const char*)h;
    const unsigned offp = (unsigned)(p * 8);   // bytes; lane owns 4 fp16 (8B)

    float acc[4] = {};
    float den = 0.f;

    for (int base = 0; base < degp; base += 64) {
        float av = 0.f;
        int sc = 0;
        int e = base + lane;
        if (e < degp) {
            int s = csr[off0 + e];
            if (s >= 0) {
                sc = s;
                float l = als[s] + aldh;
                l = l > 0.f ? l : 0.2f * l;
                av = __expf(l);
            }
        }
        alpS[wid][lane] = av;
        csrS[wid][lane] = sc;

        int qn = (degp - base) >> 2; if (qn > 16) qn = 16;
        for (int qq = g; qq < qn; qq += 4) {
            int4 cs = *(const int4*)&csrS[wid][qq * 4];
            f32x4 af = *(const f32x4*)&alpS[wid][qq * 4];
            uint2 h0 = *(const uint2*)(hB + (size_t)((((unsigned)cs.x) << 7) + offp));
            uint2 h1 = *(const uint2*)(hB + (size_t)((((unsigned)cs.y) << 7) + offp));
            uint2 h2 = *(const uint2*)(hB + (size_t)((((unsigned)cs.z) << 7) + offp));
            uint2 h3 = *(const uint2*)(hB + (size_t)((((unsigned)cs.w) << 7) + offp));
            den += (af[0] + af[1]) + (af[2] + af[3]);
            fma_mix_lo(acc[0], af[0], h0.x);
            fma_mix_hi(acc[1], af[0], h0.x);
            fma_mix_lo(acc[2], af[0], h0.y);
            fma_mix_hi(acc[3], af[0], h0.y);
            fma_mix_lo(acc[0], af[1], h1.x);
            fma_mix_hi(acc[1], af[1], h1.x);
            fma_mix_lo(acc[2], af[1], h1.y);
            fma_mix_hi(acc[3], af[1], h1.y);
            fma_mix_lo(acc[0], af[2], h2.x);
            fma_mix_hi(acc[1], af[2], h2.x);
            fma_mix_lo(acc[2], af[2], h2.y);
            fma_mix_hi(acc[3], af[2], h2.y);
            fma_mix_lo(acc[0], af[3], h3.x);
            fma_mix_hi(acc[1], af[3], h3.x);
            fma_mix_lo(acc[2], af[3], h3.y);
            fma_mix_hi(acc[3], af[3], h3.y);
        }
    }

    den += __shfl_xor(den, 16);
    den += __shfl_xor(den, 32);
#pragma unroll
    for (int j = 0; j < 4; ++j) {
        acc[j] += __shfl_xor(acc[j], 16);
        acc[j] += __shfl_xor(acc[j], 32);
    }
    if (g == 0) {
        float inv = 1.f / den;
        f32x4 o;
#pragma unroll
        for (int j = 0; j < 4; ++j)
            o[j] = acc[j] * inv + bias[p * 4 + j];
        *((f32x4*)(outp + (size_t)n * 64 + p * 4)) = o;
    }
}

// --------------------------------------------------------------------------
extern "C" void kernel_launch(void* const* d_in, const int* in_sizes, int n_in,
                              void* d_out, int out_size, void* d_ws, size_t ws_size,
                              hipStream_t stream)
{
    const float* x   = (const float*)d_in[0];
    const int*   ei  = (const int*)d_in[1];
    const float* W1  = (const float*)d_in[2];
    const float* as1 = (const float*)d_in[3];
    const float* ad1 = (const float*)d_in[4];
    const float* b1  = (const float*)d_in[5];
    const float* W2  = (const float*)d_in[6];
    const float* as2 = (const float*)d_in[7];
    const float* ad2 = (const float*)d_in[8];
    const float* b2  = (const float*)d_in[9];
    const float* W3  = (const float*)d_in[10];
    const float* as3 = (const float*)d_in[11];
    const float* ad3 = (const float*)d_in[12];
    const float* b3  = (const float*)d_in[13];

    const int DIN = 256, HC = 512, DOUT = 64;
    const int EXT = 64;                 // was/wad + zero-pad extension rows
    int N = in_sizes[0] / DIN;
    int E = in_sizes[1] / 2;
    int Mcap = E + 4 * N;  // capacity for 4-padded CSR

    // workspace carve-up
    char* w = (char*)d_ws;
    auto alloc = [&](size_t bytes) -> char* {
        char* p = w;
        w += (bytes + 255) & ~(size_t)255;
        return p;
    };
    // deg + tot first, contiguous -> ONE upfront memset
    int* deg    = (int*)alloc((size_t)N * 4);
    int* tot    = (int*)alloc(4);
    char* zend  = w;                       // end of zeroed span
    int* cur    = (int*)alloc((size_t)N * 4);
    int* off    = (int*)alloc((size_t)(N + 1) * 4);
    int* csr    = (int*)alloc((size_t)Mcap * 4);
    unsigned short* W1T = (unsigned short*)alloc((size_t)(HC + EXT) * DIN * 2);
    unsigned short* W2T = (unsigned short*)alloc((size_t)(HC + EXT) * HC * 2);
    unsigned short* W3T = (unsigned short*)alloc((size_t)DOUT * HC * 2);
    unsigned short* xb  = (unsigned short*)alloc((size_t)N * DIN * 2);
    unsigned short* act = (unsigned short*)alloc((size_t)N * HC * 2);
    unsigned short* hb  = (unsigned short*)alloc((size_t)N * HC * 2);
    unsigned short* hb3 = (unsigned short*)alloc((size_t)N * DOUT * 2);  // fp16 h (layer 3)
    float* als   = (float*)alloc((size_t)N * 4 * 4);
    float* ald   = (float*)alloc((size_t)N * 4 * 4);

    // ---- build: memset(deg+tot) -> prep(+was/wad, vectorized) -> alloc -> fill
    hipMemsetAsync(deg, 0, (size_t)(zend - (char*)deg), stream);
    int prep_total = DIN * HC + HC * HC + HC * DOUT + (N * DIN) / 4 + (Mcap + 3) / 4
                   + E + 8 * DIN + 8 * HC + 56 * DIN + 56 * HC;
    k_prep<<<(prep_total + 255) / 256, 256, 0, stream>>>(
        W1, W1T, W2, W2T, W3, W3T, x, xb, csr, Mcap, ei, E, deg,
        as1, ad1, as2, ad2, DIN, HC, DOUT, N);
    k_alloc<<<(N + 255) / 256, 256, 0, stream>>>(deg, off, cur, tot, N);
    k_fill<<<(E + N + 255) / 256, 256, 0, stream>>>(ei, E, N, cur, csr);

    int tiles_m = (N + 63) / 64;
    auto gemm_blocks = [&](int tn) { return (tiles_m * tn + 3) / 4; };
    int tm128 = (N + 127) / 128;
    int tiles_n12 = HC / 64 + 1;        // 8 data tiles + 1 al tile
    int nwave_blocks = (N + 3) / 4;
    int nodeBlocks = (N + 3) / 4;

    // ---- layer 1 ----
    k_gemm_lds<<<tm128 * tiles_n12, 256, 0, stream>>>(xb, W1T, hb, N, DIN, HC, tiles_n12, als, ald);
    k_aggr4f<true><<<4 * nodeBlocks, 256, 0, stream>>>(hb, als, ald, off, deg, csr, b1, act, N, nodeBlocks);

    // ---- layer 2 ----
    k_gemm_lds<<<tm128 * tiles_n12, 256, 0, stream>>>(act, W2T, hb, N, HC, HC, tiles_n12, als, ald);
    k_aggr4f<true><<<4 * nodeBlocks, 256, 0, stream>>>(hb, als, ald, off, deg, csr, b2, act, N, nodeBlocks);

    // ---- layer 3 (fp16 h path; Nc=64, al fused into GEMM epilogue) ----
    k_gemm<true, true><<<gemm_blocks(1), 256, 0, stream>>>(
        act, W3T, hb3, N, HC, DOUT, 1, as3, ad3, als, ald);
    k_aggr1c<<<nwave_blocks, 256, 0, stream>>>(hb3, als, ald, off, deg, csr, b3, (float*)d_out, N);
}